// Round 4
// baseline (525.999 us; speedup 1.0000x reference)
//
#include <hip/hip_runtime.h>
#include <hip/hip_bf16.h>

#define NB   16
#define SQL  2048
#define SKL  2048
#define DKL  64
#define DVL  64
#define NE   (NB * SQL * DKL)   /* 2,097,152 elems per tensor */

typedef __attribute__((ext_vector_type(8))) short short8;
typedef __attribute__((ext_vector_type(4))) short s16x4;
typedef __attribute__((ext_vector_type(4))) float f32x4;

#define VST 56   // Vt LDS row stride (elems): 112B rows, 16B-aligned, 2-way bank alias (free)
#define PST 56   // P  LDS row stride (elems)

#define SCALE_LOG2E 0.1803368801111204f  /* (1/sqrt(64)) * log2(e) */
#define EXP2F(x) __builtin_amdgcn_exp2f(x)

__device__ __forceinline__ short f2bf(float x) {  // rne f32 -> bf16 bits
    unsigned u = __builtin_bit_cast(unsigned, x);
    u = (u + 0x7fffu + ((u >> 16) & 1u)) >> 16;
    return (short)u;
}
__device__ __forceinline__ float bf2f(short s) {
    return __builtin_bit_cast(float, ((unsigned)(unsigned short)s) << 16);
}

// ---------- prep: split Q,K into bf16 hi/lo; cast V to bf16 ----------
__global__ __launch_bounds__(256)
void prep(const float* __restrict__ Q, const float* __restrict__ K,
          const float* __restrict__ V, short* __restrict__ ws)
{
    short* qhi = ws;
    short* qlo = ws + (size_t)NE;
    short* khi = ws + (size_t)2 * NE;
    short* klo = ws + (size_t)3 * NE;
    short* vb  = ws + (size_t)4 * NE;

    size_t i4 = ((size_t)blockIdx.x * 256 + threadIdx.x) * 4;
    if (i4 >= NE) return;

    f32x4 q = *(const f32x4*)(Q + i4);
    f32x4 k = *(const f32x4*)(K + i4);
    f32x4 v = *(const f32x4*)(V + i4);
    s16x4 qh, ql, kh, kl, vv;
    #pragma unroll
    for (int j = 0; j < 4; j++) {
        qh[j] = f2bf(q[j]);  ql[j] = f2bf(q[j] - bf2f(qh[j]));
        kh[j] = f2bf(k[j]);  kl[j] = f2bf(k[j] - bf2f(kh[j]));
        vv[j] = f2bf(v[j]);
    }
    *(s16x4*)(qhi + i4) = qh;
    *(s16x4*)(qlo + i4) = ql;
    *(s16x4*)(khi + i4) = kh;
    *(s16x4*)(klo + i4) = kl;
    *(s16x4*)(vb  + i4) = vv;
}

// s-tiles for 32 keys: s = Qhi*Khi + Qhi*Klo + Qlo*Khi  (split-bf16, ~fp32 accurate)
__device__ __forceinline__ void qk_tiles(const short* __restrict__ khi,
                                         const short* __restrict__ klo, int kb,
                                         int l15, int quad,
                                         short8 qa0h, short8 qa1h,
                                         short8 qa0l, short8 qa1l,
                                         f32x4& s0, f32x4& s1) {
    size_t o0 = (size_t)(kb + l15) * DKL + quad * 8;
    size_t o1 = (size_t)(kb + 16 + l15) * DKL + quad * 8;
    short8 h0l = *(const short8*)(khi + o0);
    short8 h0h = *(const short8*)(khi + o0 + 32);
    short8 h1l = *(const short8*)(khi + o1);
    short8 h1h = *(const short8*)(khi + o1 + 32);
    short8 l0l = *(const short8*)(klo + o0);
    short8 l0h = *(const short8*)(klo + o0 + 32);
    short8 l1l = *(const short8*)(klo + o1);
    short8 l1h = *(const short8*)(klo + o1 + 32);
    f32x4 z = {0.f, 0.f, 0.f, 0.f};
    s0 = __builtin_amdgcn_mfma_f32_16x16x32_bf16(qa0h, h0l, z, 0, 0, 0);
    s0 = __builtin_amdgcn_mfma_f32_16x16x32_bf16(qa1h, h0h, s0, 0, 0, 0);
    s0 = __builtin_amdgcn_mfma_f32_16x16x32_bf16(qa0h, l0l, s0, 0, 0, 0);
    s0 = __builtin_amdgcn_mfma_f32_16x16x32_bf16(qa1h, l0h, s0, 0, 0, 0);
    s0 = __builtin_amdgcn_mfma_f32_16x16x32_bf16(qa0l, h0l, s0, 0, 0, 0);
    s0 = __builtin_amdgcn_mfma_f32_16x16x32_bf16(qa1l, h0h, s0, 0, 0, 0);
    s1 = __builtin_amdgcn_mfma_f32_16x16x32_bf16(qa0h, h1l, z, 0, 0, 0);
    s1 = __builtin_amdgcn_mfma_f32_16x16x32_bf16(qa1h, h1h, s1, 0, 0, 0);
    s1 = __builtin_amdgcn_mfma_f32_16x16x32_bf16(qa0h, l1l, s1, 0, 0, 0);
    s1 = __builtin_amdgcn_mfma_f32_16x16x32_bf16(qa1h, l1h, s1, 0, 0, 0);
    s1 = __builtin_amdgcn_mfma_f32_16x16x32_bf16(qa0l, h1l, s1, 0, 0, 0);
    s1 = __builtin_amdgcn_mfma_f32_16x16x32_bf16(qa1l, h1h, s1, 0, 0, 0);
}

__global__ __launch_bounds__(256)
void attn_fwd(const short* __restrict__ ws, const int* __restrict__ mask,
              float* __restrict__ out, float* __restrict__ attn)
{
    __shared__ float s_bias[SKL];          // 8 KB
    __shared__ short s_vt[64 * VST];       // 7 KB: V-tile transposed [v][k]
    __shared__ short s_p[4 * 16 * PST];    // 7 KB: per-wave P tile [q][k]

    const int tid  = threadIdx.x;
    const int wave = tid >> 6;
    const int l15  = tid & 15;
    const int quad = (tid & 63) >> 4;

    const int b     = blockIdx.x >> 5;
    const int qblk  = blockIdx.x & 31;
    const int qbase = qblk * 64 + wave * 16;

    for (int i = tid; i < SKL; i += 256)
        s_bias[i] = mask[b * SKL + i] ? 0.0f : -1e9f;
    __syncthreads();

    const short* qhi = ws +             (size_t)(b * SQL + qbase) * DKL;
    const short* qlo = ws + (size_t)NE + (size_t)(b * SQL + qbase) * DKL;
    const short* khi = ws + (size_t)2 * NE + (size_t)b * SKL * DKL;
    const short* klo = ws + (size_t)3 * NE + (size_t)b * SKL * DKL;
    const short* vb  = ws + (size_t)4 * NE + (size_t)b * SKL * DVL;

    short8 qa0h = *(const short8*)(qhi + (size_t)l15 * DKL + quad * 8);
    short8 qa1h = *(const short8*)(qhi + (size_t)l15 * DKL + 32 + quad * 8);
    short8 qa0l = *(const short8*)(qlo + (size_t)l15 * DKL + quad * 8);
    short8 qa1l = *(const short8*)(qlo + (size_t)l15 * DKL + 32 + quad * 8);

    // ---------- sweep 1: denominators ----------
    float lsum[4] = {0.f, 0.f, 0.f, 0.f};
    for (int kb = 0; kb < SKL; kb += 32) {
        f32x4 s0, s1;
        qk_tiles(khi, klo, kb, l15, quad, qa0h, qa1h, qa0l, qa1l, s0, s1);
        float bias0 = s_bias[kb + l15];
        float bias1 = s_bias[kb + 16 + l15];
        #pragma unroll
        for (int r = 0; r < 4; r++) {
            lsum[r] += EXP2F(fmaf(s0[r], SCALE_LOG2E, bias0));
            lsum[r] += EXP2F(fmaf(s1[r], SCALE_LOG2E, bias1));
        }
    }
    #pragma unroll
    for (int off = 1; off <= 8; off <<= 1) {
        #pragma unroll
        for (int r = 0; r < 4; r++)
            lsum[r] += __shfl_xor(lsum[r], off, 64);
    }
    float inv_l[4];
    #pragma unroll
    for (int r = 0; r < 4; r++) inv_l[r] = 1.0f / lsum[r];

    // ---------- sweep 2: attn write + P·V ----------
    f32x4 acc[4];
    #pragma unroll
    for (int vt = 0; vt < 4; vt++) { f32x4 z = {0.f,0.f,0.f,0.f}; acc[vt] = z; }

    const int vk  = tid & 31;
    const int vv0 = (tid >> 5) * 8;
    short* pw = s_p + wave * 16 * PST;

    for (int kb = 0; kb < SKL; kb += 32) {
        __syncthreads();
        {   // stage V chunk transposed: s_vt[v][k] = V[kb+k][v]
            short8 vvv = *(const short8*)(vb + (size_t)(kb + vk) * DVL + vv0);
            #pragma unroll
            for (int j = 0; j < 8; j++)
                s_vt[(vv0 + j) * VST + vk] = vvv[j];
        }
        __syncthreads();

        f32x4 s0, s1;
        qk_tiles(khi, klo, kb, l15, quad, qa0h, qa1h, qa0l, qa1l, s0, s1);
        float bias0 = s_bias[kb + l15];
        float bias1 = s_bias[kb + 16 + l15];

        const size_t arow = (size_t)(b * SQL + qbase + quad * 4) * SKL + kb;
        #pragma unroll
        for (int r = 0; r < 4; r++) {
            float p0 = EXP2F(fmaf(s0[r], SCALE_LOG2E, bias0)) * inv_l[r];
            float p1 = EXP2F(fmaf(s1[r], SCALE_LOG2E, bias1)) * inv_l[r];
            attn[arow + (size_t)r * SKL + l15]      = p0;   // fp32 attn output
            attn[arow + (size_t)r * SKL + 16 + l15] = p1;
            pw[(quad * 4 + r) * PST + l15]      = f2bf(p0); // C-layout -> LDS
            pw[(quad * 4 + r) * PST + 16 + l15] = f2bf(p1);
        }

        short8 pa = *(const short8*)(pw + l15 * PST + quad * 8);
        #pragma unroll
        for (int vt = 0; vt < 4; vt++) {
            short8 bvv = *(const short8*)(s_vt + (vt * 16 + l15) * VST + quad * 8);
            acc[vt] = __builtin_amdgcn_mfma_f32_16x16x32_bf16(pa, bvv, acc[vt], 0, 0, 0);
        }
    }

    #pragma unroll
    for (int vt = 0; vt < 4; vt++) {
        #pragma unroll
        for (int r = 0; r < 4; r++)
            out[(size_t)(b * SQL + qbase + quad * 4 + r) * DVL + vt * 16 + l15] =
                acc[vt][r];
    }
}

extern "C" void kernel_launch(void* const* d_in, const int* in_sizes, int n_in,
                              void* d_out, int out_size, void* d_ws, size_t ws_size,
                              hipStream_t stream) {
    const float* Q    = (const float*)d_in[0];
    const float* K    = (const float*)d_in[1];
    const float* V    = (const float*)d_in[2];
    const int*   mask = (const int*)d_in[3];
    float* out  = (float*)d_out;
    float* attn = out + (size_t)NB * SQL * DVL;  // tuple order: (output, attn)
    short* ws   = (short*)d_ws;                  // 5*NE shorts = 20 MB

    prep<<<dim3(NE / (256 * 4)), dim3(256), 0, stream>>>(Q, K, V, ws);
    attn_fwd<<<dim3(NB * (SQL / 64)), dim3(256), 0, stream>>>(ws, mask, out, attn);
}